// Round 13
// baseline (344.923 us; speedup 1.0000x reference)
//
#include <hip/hip_runtime.h>
#include <math.h>

#define HH 512
#define PP 256
#define LL 4096
#define NB 8
#define BM 128
#define BN 128
#define BK 32
#define KTILES (HH / BK)

typedef __attribute__((ext_vector_type(4))) float f32x4;
typedef __attribute__((ext_vector_type(8))) __bf16 bf16x8;
typedef __attribute__((ext_vector_type(4))) unsigned short us4;
typedef __attribute__((ext_vector_type(8))) unsigned short us8;

// ws layout:
// [0, 512KB)      M1  (2P x H) bf16  rows 0..255 Re(B_bar), 256..511 Im(B_bar)
// [512KB, 1MB)    C2  (H x 2P) bf16  cols 0..255 2Re(C), 256..511 -2Im(C)
// [1MB, 1MB+2KB)  lam (P x 2) f32
// [2MB, 2MB+32MB) Bu bf16 (NB, 2P, L), scanned in place -> xs

__device__ __forceinline__ unsigned short f2bf(float x) {
  unsigned int u = __builtin_bit_cast(unsigned int, x);
  return (unsigned short)((u + 0x7fffu + ((u >> 16) & 1u)) >> 16);
}
__device__ __forceinline__ float bf2f(unsigned short h) {
  unsigned int u = ((unsigned int)h) << 16;
  return __builtin_bit_cast(float, u);
}
__device__ __forceinline__ float gelu_exact(float x) {
  return 0.5f * x * (1.0f + erff(x * 0.70710678118654752f));
}
__device__ __forceinline__ void gl_lds16(const void* g, void* l) {
  __builtin_amdgcn_global_load_lds(
      (const __attribute__((address_space(1))) unsigned int*)g,
      (__attribute__((address_space(3))) unsigned int*)l, 16, 0, 0);
}

__global__ __launch_bounds__(256) void precompute_params(
    const float* __restrict__ Lre, const float* __restrict__ Lim,
    const float* __restrict__ Bmat, const float* __restrict__ Cmat,
    const float* __restrict__ logstep,
    unsigned short* __restrict__ M1, unsigned short* __restrict__ C2,
    float* __restrict__ lam)
{
  const int p = blockIdx.x;
  const int t = threadIdx.x;
  const float re = Lre[p], im = Lim[p];
  const float step = expf(logstep[p]);
  const float er  = expf(re * step);
  const float lbr = er * cosf(im * step);
  const float lbi = er * sinf(im * step);
  if (t == 0) { lam[2*p] = lbr; lam[2*p+1] = lbi; }
  const float den = re*re + im*im;
  const float nr = lbr - 1.0f, ni = lbi;
  const float gr = (nr*re + ni*im) / den;
  const float gi = (ni*re - nr*im) / den;
  for (int h = t; h < HH; h += 256) {
    const float br = Bmat[(p*HH + h)*2 + 0];
    const float bi = Bmat[(p*HH + h)*2 + 1];
    M1[p*HH + h]        = f2bf(gr*br - gi*bi);   // Re(B_bar)
    M1[(PP+p)*HH + h]   = f2bf(gr*bi + gi*br);   // Im(B_bar)
    const float cr = Cmat[(h*PP + p)*2 + 0];
    const float ci = Cmat[(h*PP + p)*2 + 1];
    C2[h*(2*PP) + p]      = f2bf( 2.0f * cr);
    C2[h*(2*PP) + PP + p] = f2bf(-2.0f * ci);
  }
}

// Fused NN-GEMM (R8 pipeline, 24 KiB LDS -> 6 blocks/CU):
// C[b](512x4096) = A(512x512, k-contig bf16) x Bsrc[b](512k x 4096n)
// A double-buffered (2 x 8 KiB, async gl_lds must cross a barrier);
// B SINGLE-buffered (8 KiB, reg-staged): B_WRITE(t+1) happens after the
// post-COMPUTE barrier (all waves done reading tile t), and its visibility
// for step t+1 is published by each wave's lgkmcnt(0) + the next pre-COMPUTE
// barrier. 2 barriers/step, same as R8, but 6 blocks/CU instead of 4.
// vmcnt ring: B_WRITE's reg dependency implicitly retires the 4 B-loads
// (keeping <=2 A-lds in flight); next step's vmcnt(6) retires exactly them.
// Swizzle (both-sides involution): row r, 4 slots of 16B;
// stored slot s holds source k-oct s ^ g(r), g(r) = (r>>2)&3.
template<bool SRCF32, bool EPI>
__global__ __launch_bounds__(256, 6) void s5_gemm_fused(
    const unsigned short* __restrict__ A,
    const void* __restrict__ Bsrc,
    void* __restrict__ Cout,
    const float* __restrict__ Dv,
    const float* __restrict__ Ug)
{
  // XCD-aware bijective swizzle of flattened block id (nwg = 1024, %8==0)
  const int nbx = LL / BN;              // 32
  const int nby = HH / BM;              // 4
  const int nwg = nbx * nby * NB;       // 1024
  const int hw  = blockIdx.x + nbx * (blockIdx.y + nby * blockIdx.z);
  const int bid = (hw & 7) * (nwg >> 3) + (hw >> 3);
  const int bx = bid % nbx;
  const int by = (bid / nbx) % nby;
  const int b  = bid / (nbx * nby);

  const int n0 = bx * BN;
  const int m0 = by * BM;
  const int tid  = threadIdx.x;
  const int lane = tid & 63;
  const int w    = tid >> 6;
  const int lr = lane & 15, lg = lane >> 4;
  const int wm = (w >> 1) * 64, wn = (w & 1) * 64;

  // 24 KiB: [A buf0 | A buf1 | B single], each BM*BK elems (8 KiB)
  __shared__ __align__(16) unsigned short LB[3 * BM * BK];
  unsigned short* const Bs = LB + 2 * BM * BK;
#define ASEL(s) (LB + (s) * BM * BK)

  f32x4 acc[4][4];
#pragma unroll
  for (int i = 0; i < 4; ++i)
#pragma unroll
    for (int j = 0; j < 4; ++j) acc[i][j] = f32x4{0.0f, 0.0f, 0.0f, 0.0f};

  // fragment read offset (elems): slot = lg ^ g(row), g(row) = (lr>>2)&3
  const int swz = (lg ^ ((lr >> 2) & 3)) * 8;

  // B staging decomposition: nq = n-quad (4 n's), ko = k-quad group (4 k's)
  const int nq = tid & 31;   // n2 = nq*4 + j
  const int ko = tid >> 5;   // k rows ko*4 .. ko*4+3 ; k-oct = ko>>1, half = ko&1

  const float*          BsF = (const float*)Bsrc          + (size_t)b * HH * LL;
  const unsigned short* BsH = (const unsigned short*)Bsrc + (size_t)b * HH * LL;

  f32x4 bv[4];  // G1: f32 source regs
  us4   bh[4];  // G2: bf16 source regs

#define STAGE_A(k0, sel)                                                       \
  {                                                                            \
    _Pragma("unroll")                                                          \
    for (int i = 0; i < 2; ++i) {                                              \
      const int c   = i * 256 + tid;                                           \
      const int row = c >> 2;                                                  \
      const int ks  = (c & 3) ^ ((c >> 4) & 3);                                \
      gl_lds16(A + (size_t)(m0 + row) * HH + (k0) + ks * 8, &ASEL(sel)[c * 8]);\
    }                                                                          \
  }

#define B_LOAD(k0)                                                             \
  {                                                                            \
    _Pragma("unroll")                                                          \
    for (int r = 0; r < 4; ++r) {                                              \
      if (SRCF32)                                                              \
        bv[r] = *(const f32x4*)(BsF + (size_t)((k0) + ko * 4 + r) * LL + n0 + nq * 4); \
      else                                                                     \
        bh[r] = *(const us4*)(BsH + (size_t)((k0) + ko * 4 + r) * LL + n0 + nq * 4);   \
    }                                                                          \
  }

  // B write into the single Bs buffer: thread's 4 k's are half (ko&1) of
  // k-oct (ko>>1); stored slot = (ko>>1) ^ g(n2)
#define B_WRITE()                                                              \
  {                                                                            \
    _Pragma("unroll")                                                          \
    for (int j = 0; j < 4; ++j) {                                              \
      const int n2 = nq * 4 + j;                                               \
      us4 wv;                                                                  \
      _Pragma("unroll")                                                        \
      for (int r = 0; r < 4; ++r)                                              \
        wv[r] = SRCF32 ? f2bf(bv[r][j]) : bh[r][j];                            \
      const int slot = (ko >> 1) ^ ((n2 >> 2) & 3);                            \
      *(us4*)&Bs[n2 * BK + slot * 8 + (ko & 1) * 4] = wv;                      \
    }                                                                          \
  }

#define SB __builtin_amdgcn_sched_barrier(0)
#define BAR __builtin_amdgcn_s_barrier()

  // prologue: tile 0 into A buf0 + Bs, full drain once
  B_LOAD(0);
  STAGE_A(0, 0);
  B_WRITE();
  __syncthreads();

  for (int t = 0; t < KTILES; ++t) {
    const int cur = t & 1;
    const bool more = (t + 1 < KTILES);
    if (more) {
      B_LOAD((t + 1) * BK);                       // 4 VMEM (issue early)
      if (cur) STAGE_A((t + 1) * BK, 0) else STAGE_A((t + 1) * BK, 1);  // 2 VMEM
      asm volatile("s_waitcnt vmcnt(6)" ::: "memory");  // retire prior step's A-lds
    } else {
      asm volatile("s_waitcnt vmcnt(0)" ::: "memory");
    }
    SB; BAR; SB;        // all waves: A[cur] staged, Bs writes of t-1 visible

    bf16x8 aF[4], bF[4];
#pragma unroll
    for (int f = 0; f < 4; ++f) {
      aF[f] = *(const bf16x8*)&ASEL(cur)[(wm + f * 16 + lr) * BK + swz];
      bF[f] = *(const bf16x8*)&Bs[(wn + f * 16 + lr) * BK + swz];
    }
#pragma unroll
    for (int fm = 0; fm < 4; ++fm)
#pragma unroll
      for (int fn = 0; fn < 4; ++fn)
        acc[fm][fn] = __builtin_amdgcn_mfma_f32_16x16x32_bf16(
            aF[fm], bF[fn], acc[fm][fn], 0, 0, 0);

    SB; BAR; SB;        // all waves done reading Bs (WAR guard)
    if (more) {
      B_WRITE();        // overwrite Bs with tile t+1 (waits bv regs only)
      asm volatile("s_waitcnt lgkmcnt(0)" ::: "memory");  // publish before next BAR
      SB;
    }
  }
#undef STAGE_A
#undef B_LOAD
#undef B_WRITE
#undef SB
#undef BAR

  if (!EPI) {
    unsigned short* C = (unsigned short*)Cout + (size_t)b * HH * LL;
#pragma unroll
    for (int fm = 0; fm < 4; ++fm)
#pragma unroll
      for (int r = 0; r < 4; ++r) {
        const int row = m0 + wm + fm*16 + lg*4 + r;
#pragma unroll
        for (int fn = 0; fn < 4; ++fn) {
          const int col = n0 + wn + fn*16 + lr;
          C[(size_t)row * LL + col] = f2bf(acc[fm][fn][r]);
        }
      }
  } else {
    float* C = (float*)Cout + (size_t)b * HH * LL;
    const float* Ub = Ug + (size_t)b * HH * LL;
#pragma unroll
    for (int fm = 0; fm < 4; ++fm)
#pragma unroll
      for (int r = 0; r < 4; ++r) {
        const int row = m0 + wm + fm*16 + lg*4 + r;
        const float dv = Dv[row];
#pragma unroll
        for (int fn = 0; fn < 4; ++fn) {
          const int col = n0 + wn + fn*16 + lr;
          const float y = fmaf(dv, Ub[(size_t)row * LL + col], acc[fm][fn][r]);
          C[(size_t)row * LL + col] = gelu_exact(y);
        }
      }
  }
#undef ASEL
}

// chunked parallel scan per (b,p): x_l = lam*x_{l-1} + Bu_l (complex), bf16 in place.
// Intra-wave affine scan via __shfl_up (6 rounds) + 1-barrier cross-wave combine.
__global__ __launch_bounds__(256) void s5_scan(
    unsigned short* __restrict__ Bu, const float* __restrict__ lam)
{
  const int p = blockIdx.x;
  const int b = blockIdx.y;
  const int t = threadIdx.x;
  const int lane = t & 63;
  const int w    = t >> 6;
  unsigned short* rowr = Bu + ((size_t)b*2*PP + p)      * LL;
  unsigned short* rowi = Bu + ((size_t)b*2*PP + PP + p) * LL;

  const float lre = lam[2*p], lim = lam[2*p+1];

  float br[16], bi[16];
  {
    us8 v0 = *(const us8*)&rowr[t*16];
    us8 v1 = *(const us8*)&rowr[t*16 + 8];
    us8 w0 = *(const us8*)&rowi[t*16];
    us8 w1 = *(const us8*)&rowi[t*16 + 8];
#pragma unroll
    for (int j = 0; j < 8; ++j) {
      br[j] = bf2f(v0[j]); br[8+j] = bf2f(v1[j]);
      bi[j] = bf2f(w0[j]); bi[8+j] = bf2f(w1[j]);
    }
  }

  float xr = 0.0f, xi = 0.0f;
#pragma unroll
  for (int j = 0; j < 16; ++j) {
    const float nr = fmaf(lre, xr, fmaf(-lim, xi, br[j]));
    const float ni = fmaf(lre, xi, fmaf( lim, xr, bi[j]));
    xr = nr; xi = ni;
  }

  float mre = lre, mim = lim;
#pragma unroll
  for (int s = 0; s < 4; ++s) {
    const float n2 = mre*mre - mim*mim;
    mim = 2.0f*mre*mim; mre = n2;
  }

  float Sr = xr, Si = xi;
  float pwr[6], pwi[6];
#pragma unroll
  for (int rnd = 0; rnd < 6; ++rnd) {
    pwr[rnd] = mre; pwi[rnd] = mim;
    const int off = 1 << rnd;
    const float vr = __shfl_up(Sr, off);
    const float vi = __shfl_up(Si, off);
    if (lane >= off) {
      Sr = fmaf(mre, vr, fmaf(-mim, vi, Sr));
      Si = fmaf(mre, vi, fmaf( mim, vr, Si));
    }
    const float n2 = mre*mre - mim*mim;
    mim = 2.0f*mre*mim; mre = n2;
  }

  __shared__ float Twr[4], Twi[4];
  if (lane == 63) { Twr[w] = Sr; Twi[w] = Si; }
  __syncthreads();

  float cwr = 0.0f, cwi = 0.0f;
  for (int v = 0; v < w; ++v) {
    const float nr = fmaf(mre, cwr, fmaf(-mim, cwi, Twr[v]));
    const float ni = fmaf(mre, cwi, fmaf( mim, cwr, Twi[v]));
    cwr = nr; cwi = ni;
  }

  float Er = __shfl_up(Sr, 1);
  float Ei = __shfl_up(Si, 1);
  if (lane == 0) { Er = 0.0f; Ei = 0.0f; }

  float plr = 1.0f, pli = 0.0f;
#pragma unroll
  for (int rnd = 0; rnd < 6; ++rnd) {
    if ((lane >> rnd) & 1) {
      const float nr = plr*pwr[rnd] - pli*pwi[rnd];
      const float ni = plr*pwi[rnd] + pli*pwr[rnd];
      plr = nr; pli = ni;
    }
  }

  const float cr = Er + plr*cwr - pli*cwi;
  const float ci = Ei + plr*cwi + pli*cwr;

  xr = cr; xi = ci;
  us8 o0, o1, o2, o3;
#pragma unroll
  for (int j = 0; j < 16; ++j) {
    const float nr = fmaf(lre, xr, fmaf(-lim, xi, br[j]));
    const float ni = fmaf(lre, xi, fmaf( lim, xr, bi[j]));
    xr = nr; xi = ni;
    if (j < 8) { o0[j] = f2bf(xr); o2[j] = f2bf(xi); }
    else       { o1[j-8] = f2bf(xr); o3[j-8] = f2bf(xi); }
  }
  *(us8*)&rowr[t*16]     = o0;
  *(us8*)&rowr[t*16 + 8] = o1;
  *(us8*)&rowi[t*16]     = o2;
  *(us8*)&rowi[t*16 + 8] = o3;
}

extern "C" void kernel_launch(void* const* d_in, const int* in_sizes, int n_in,
                              void* d_out, int out_size, void* d_ws, size_t ws_size,
                              hipStream_t stream) {
  (void)in_sizes; (void)n_in; (void)out_size; (void)ws_size;
  const float* in_seq = (const float*)d_in[0];
  const float* Lre    = (const float*)d_in[1];
  const float* Lim    = (const float*)d_in[2];
  const float* Bm     = (const float*)d_in[3];
  const float* Cm     = (const float*)d_in[4];
  const float* Dv     = (const float*)d_in[5];
  const float* ls     = (const float*)d_in[6];
  float* out = (float*)d_out;

  char* ws = (char*)d_ws;
  unsigned short* M1  = (unsigned short*)(ws);
  unsigned short* C2  = (unsigned short*)(ws + (512u << 10));
  float*          lam = (float*)(ws + (1u << 20));
  unsigned short* Bu  = (unsigned short*)(ws + (2u << 20));   // 32 MiB

  precompute_params<<<dim3(PP), dim3(256), 0, stream>>>(Lre, Lim, Bm, Cm, ls, M1, C2, lam);

  dim3 gg(LL/BN, HH/BM, NB);
  // G1: Bu = M1 x u   (u f32, K-strided -> fused transpose staging)
  s5_gemm_fused<true, false><<<gg, dim3(256), 0, stream>>>(M1, in_seq, Bu, nullptr, nullptr);

  s5_scan<<<dim3(PP, NB), dim3(256), 0, stream>>>(Bu, lam);

  // G2: out = gelu(C2 x xs + D*u)   (xs bf16 in Bu layout)
  s5_gemm_fused<false, true><<<gg, dim3(256), 0, stream>>>(C2, Bu, out, Dv, in_seq);
}

// Round 14
// 103.376 us; speedup vs baseline: 3.3366x; 3.3366x over previous
//
#include <hip/hip_runtime.h>
#include <math.h>

#define HH 512
#define PP 256
#define LL 4096
#define NB 8
#define BM 128
#define BN 128
#define BK 32
#define KTILES (HH / BK)

typedef __attribute__((ext_vector_type(4))) float f32x4;
typedef __attribute__((ext_vector_type(8))) __bf16 bf16x8;
typedef __attribute__((ext_vector_type(4))) unsigned short us4;
typedef __attribute__((ext_vector_type(8))) unsigned short us8;

// ws layout:
// [0, 512KB)      M1  (2P x H) bf16  rows 0..255 Re(B_bar), 256..511 Im(B_bar)
// [512KB, 1MB)    C2  (H x 2P) bf16  cols 0..255 2Re(C), 256..511 -2Im(C)
// [1MB, 1MB+2KB)  lam (P x 2) f32
// [2MB, 2MB+32MB) Bu bf16 (NB, 2P, L), scanned in place -> xs

__device__ __forceinline__ unsigned short f2bf(float x) {
  unsigned int u = __builtin_bit_cast(unsigned int, x);
  return (unsigned short)((u + 0x7fffu + ((u >> 16) & 1u)) >> 16);
}
__device__ __forceinline__ float bf2f(unsigned short h) {
  unsigned int u = ((unsigned int)h) << 16;
  return __builtin_bit_cast(float, u);
}
__device__ __forceinline__ float gelu_exact(float x) {
  return 0.5f * x * (1.0f + erff(x * 0.70710678118654752f));
}
__device__ __forceinline__ void gl_lds16(const void* g, void* l) {
  __builtin_amdgcn_global_load_lds(
      (const __attribute__((address_space(1))) unsigned int*)g,
      (__attribute__((address_space(3))) unsigned int*)l, 16, 0, 0);
}

__global__ __launch_bounds__(256) void precompute_params(
    const float* __restrict__ Lre, const float* __restrict__ Lim,
    const float* __restrict__ Bmat, const float* __restrict__ Cmat,
    const float* __restrict__ logstep,
    unsigned short* __restrict__ M1, unsigned short* __restrict__ C2,
    float* __restrict__ lam)
{
  const int p = blockIdx.x;
  const int t = threadIdx.x;
  const float re = Lre[p], im = Lim[p];
  const float step = expf(logstep[p]);
  const float er  = expf(re * step);
  const float lbr = er * cosf(im * step);
  const float lbi = er * sinf(im * step);
  if (t == 0) { lam[2*p] = lbr; lam[2*p+1] = lbi; }
  const float den = re*re + im*im;
  const float nr = lbr - 1.0f, ni = lbi;
  const float gr = (nr*re + ni*im) / den;
  const float gi = (ni*re - nr*im) / den;
  for (int h = t; h < HH; h += 256) {
    const float br = Bmat[(p*HH + h)*2 + 0];
    const float bi = Bmat[(p*HH + h)*2 + 1];
    M1[p*HH + h]        = f2bf(gr*br - gi*bi);   // Re(B_bar)
    M1[(PP+p)*HH + h]   = f2bf(gr*bi + gi*br);   // Im(B_bar)
    const float cr = Cmat[(h*PP + p)*2 + 0];
    const float ci = Cmat[(h*PP + p)*2 + 1];
    C2[h*(2*PP) + p]      = f2bf( 2.0f * cr);
    C2[h*(2*PP) + PP + p] = f2bf(-2.0f * ci);
  }
}

// Fused NN-GEMM (R8/R10-verified best): C[b](512x4096) = A(512x512) x Bsrc[b](512k x 4096n)
// BK=32, 32 KiB LDS/block -> 4 blocks/CU. Counted vmcnt, raw barriers.
// A via global_load_lds (dbuf), B reg-staged with in-register 4kx4n transpose
// (dbuf), both-sides XOR swizzle: row r, 4 slots of 16B; stored slot
// s = src ^ g(r), g(r) = (r>>2)&3; fragment read at slot lg ^ g(row).
template<bool SRCF32, bool EPI>
__global__ __launch_bounds__(256, 4) void s5_gemm_fused(
    const unsigned short* __restrict__ A,
    const void* __restrict__ Bsrc,
    void* __restrict__ Cout,
    const float* __restrict__ Dv,
    const float* __restrict__ Ug)
{
  // XCD-aware bijective swizzle of flattened block id (nwg = 1024, %8==0)
  const int nbx = LL / BN;              // 32
  const int nby = HH / BM;              // 4
  const int nwg = nbx * nby * NB;       // 1024
  const int hw  = blockIdx.x + nbx * (blockIdx.y + nby * blockIdx.z);
  const int bid = (hw & 7) * (nwg >> 3) + (hw >> 3);
  const int bx = bid % nbx;
  const int by = (bid / nbx) % nby;
  const int b  = bid / (nbx * nby);

  const int n0 = bx * BN;
  const int m0 = by * BM;
  const int tid  = threadIdx.x;
  const int lane = tid & 63;
  const int w    = tid >> 6;
  const int lr = lane & 15, lg = lane >> 4;
  const int wm = (w >> 1) * 64, wn = (w & 1) * 64;

  // 32 KiB union: [As sel0 | As sel1 | Bs sel0 | Bs sel1], each BM*BK elems;
  // reused after the K-loop as a [128][128] bf16 C-tile (EPI=false).
  __shared__ __align__(16) unsigned short LB[4 * BM * BK];
  unsigned short* const As0 = LB;
  unsigned short* const Bs0 = LB + 2 * BM * BK;
#define ASEL(s) (As0 + (s) * BM * BK)
#define BSEL(s) (Bs0 + (s) * BN * BK)

  f32x4 acc[4][4];
#pragma unroll
  for (int i = 0; i < 4; ++i)
#pragma unroll
    for (int j = 0; j < 4; ++j) acc[i][j] = f32x4{0.0f, 0.0f, 0.0f, 0.0f};

  // fragment read offset (elems): slot = lg ^ g(row), g(row) = (lr>>2)&3
  const int swz = (lg ^ ((lr >> 2) & 3)) * 8;

  // B staging decomposition: nq = n-quad (4 n's), ko = k-quad group (4 k's)
  const int nq = tid & 31;   // n2 = nq*4 + j
  const int ko = tid >> 5;   // k rows ko*4 .. ko*4+3 ; k-oct = ko>>1, half = ko&1

  const float*          BsF = (const float*)Bsrc          + (size_t)b * HH * LL;
  const unsigned short* BsH = (const unsigned short*)Bsrc + (size_t)b * HH * LL;

  f32x4 bv[4];  // G1: f32 source regs
  us4   bh[4];  // G2: bf16 source regs

  // A staging: c in [0,512), row = c>>2, slot = c&3,
  // source k-oct = (c&3) ^ g(row) = (c&3) ^ ((c>>4)&3)
#define STAGE_A(k0, sel)                                                       \
  {                                                                            \
    _Pragma("unroll")                                                          \
    for (int i = 0; i < 2; ++i) {                                              \
      const int c   = i * 256 + tid;                                           \
      const int row = c >> 2;                                                  \
      const int ks  = (c & 3) ^ ((c >> 4) & 3);                                \
      gl_lds16(A + (size_t)(m0 + row) * HH + (k0) + ks * 8, &ASEL(sel)[c * 8]);\
    }                                                                          \
  }

#define B_LOAD(k0)                                                             \
  {                                                                            \
    _Pragma("unroll")                                                          \
    for (int r = 0; r < 4; ++r) {                                              \
      if (SRCF32)                                                              \
        bv[r] = *(const f32x4*)(BsF + (size_t)((k0) + ko * 4 + r) * LL + n0 + nq * 4); \
      else                                                                     \
        bh[r] = *(const us4*)(BsH + (size_t)((k0) + ko * 4 + r) * LL + n0 + nq * 4);   \
    }                                                                          \
  }

  // B write: thread's 4 k's form half (ko&1) of k-oct (ko>>1);
  // stored slot = (ko>>1) ^ g(n2), elem off = n2*BK + slot*8 + (ko&1)*4
#define B_WRITE(sel)                                                           \
  {                                                                            \
    _Pragma("unroll")                                                          \
    for (int j = 0; j < 4; ++j) {                                              \
      const int n2 = nq * 4 + j;                                               \
      us4 wv;                                                                  \
      _Pragma("unroll")                                                        \
      for (int r = 0; r < 4; ++r)                                              \
        wv[r] = SRCF32 ? f2bf(bv[r][j]) : bh[r][j];                            \
      const int slot = (ko >> 1) ^ ((n2 >> 2) & 3);                            \
      *(us4*)&BSEL(sel)[n2 * BK + slot * 8 + (ko & 1) * 4] = wv;               \
    }                                                                          \
  }

  // prologue: stage tile 0, full drain once
  B_LOAD(0);     // issue B loads FIRST (FIFO: A-lds newest)
  STAGE_A(0, 0);
  B_WRITE(0);
  __syncthreads();

  for (int t = 0; t < KTILES; ++t) {
    const int cur = t & 1;
    const bool more = (t + 1 < KTILES);
    if (more) {
      B_LOAD((t + 1) * BK);                       // 4 VMEM (issue early)
      if (cur) STAGE_A((t + 1) * BK, 0) else STAGE_A((t + 1) * BK, 1);  // 2 VMEM
      asm volatile("s_waitcnt vmcnt(6)" ::: "memory");
    } else {
      asm volatile("s_waitcnt vmcnt(0)" ::: "memory");
    }
    __builtin_amdgcn_sched_barrier(0);
    __builtin_amdgcn_s_barrier();                 // tile-t A in LDS for all waves
    __builtin_amdgcn_sched_barrier(0);

    bf16x8 aF[4], bF[4];
#pragma unroll
    for (int f = 0; f < 4; ++f) {
      aF[f] = *(const bf16x8*)&ASEL(cur)[(wm + f * 16 + lr) * BK + swz];
      bF[f] = *(const bf16x8*)&BSEL(cur)[(wn + f * 16 + lr) * BK + swz];
    }
#pragma unroll
    for (int fm = 0; fm < 4; ++fm)
#pragma unroll
      for (int fn = 0; fn < 4; ++fn)
        acc[fm][fn] = __builtin_amdgcn_mfma_f32_16x16x32_bf16(
            aF[fm], bF[fn], acc[fm][fn], 0, 0, 0);
    if (more) {
      if (cur) B_WRITE(0) else B_WRITE(1);        // write late
    }
    asm volatile("s_waitcnt lgkmcnt(0)" ::: "memory");
    __builtin_amdgcn_sched_barrier(0);
    __builtin_amdgcn_s_barrier();                 // WAR guard for next stage
    __builtin_amdgcn_sched_barrier(0);
  }
#undef STAGE_A
#undef B_LOAD
#undef B_WRITE

  if (!EPI) {
    // bf16 C-write coalesced through the freed 32 KiB LDS
#pragma unroll
    for (int fm = 0; fm < 4; ++fm)
#pragma unroll
      for (int r = 0; r < 4; ++r) {
        const int row = wm + fm * 16 + lg * 4 + r;
#pragma unroll
        for (int fn = 0; fn < 4; ++fn) {
          const int col = wn + fn * 16 + lr;
          LB[row * 128 + col] = f2bf(acc[fm][fn][r]);
        }
      }
    __syncthreads();
    unsigned short* C = (unsigned short*)Cout + (size_t)b * HH * LL;
#pragma unroll
    for (int pass = 0; pass < 8; ++pass) {
      const int chunk = pass * 256 + tid;   // 2048 us8 chunks, 16/row
      const int row = chunk >> 4;
      const int c8  = chunk & 15;
      us8 v = *(const us8*)&LB[row * 128 + c8 * 8];
      *(us8*)(C + (size_t)(m0 + row) * LL + n0 + c8 * 8) = v;
    }
  } else {
    float* C = (float*)Cout + (size_t)b * HH * LL;
    const float* Ub = Ug + (size_t)b * HH * LL;
#pragma unroll
    for (int fm = 0; fm < 4; ++fm)
#pragma unroll
      for (int r = 0; r < 4; ++r) {
        const int row = m0 + wm + fm*16 + lg*4 + r;
        const float dv = Dv[row];
#pragma unroll
        for (int fn = 0; fn < 4; ++fn) {
          const int col = n0 + wn + fn*16 + lr;
          const float y = fmaf(dv, Ub[(size_t)row * LL + col], acc[fm][fn][r]);
          C[(size_t)row * LL + col] = gelu_exact(y);
        }
      }
  }
#undef ASEL
#undef BSEL
}

// chunked parallel scan per (b,p): x_l = lam*x_{l-1} + Bu_l (complex), bf16 in place.
// Intra-wave affine scan via __shfl_up (6 rounds) + 1-barrier cross-wave combine.
__global__ __launch_bounds__(256) void s5_scan(
    unsigned short* __restrict__ Bu, const float* __restrict__ lam)
{
  const int p = blockIdx.x;
  const int b = blockIdx.y;
  const int t = threadIdx.x;
  const int lane = t & 63;
  const int w    = t >> 6;
  unsigned short* rowr = Bu + ((size_t)b*2*PP + p)      * LL;
  unsigned short* rowi = Bu + ((size_t)b*2*PP + PP + p) * LL;

  const float lre = lam[2*p], lim = lam[2*p+1];

  float br[16], bi[16];
  {
    us8 v0 = *(const us8*)&rowr[t*16];
    us8 v1 = *(const us8*)&rowr[t*16 + 8];
    us8 w0 = *(const us8*)&rowi[t*16];
    us8 w1 = *(const us8*)&rowi[t*16 + 8];
#pragma unroll
    for (int j = 0; j < 8; ++j) {
      br[j] = bf2f(v0[j]); br[8+j] = bf2f(v1[j]);
      bi[j] = bf2f(w0[j]); bi[8+j] = bf2f(w1[j]);
    }
  }

  float xr = 0.0f, xi = 0.0f;
#pragma unroll
  for (int j = 0; j < 16; ++j) {
    const float nr = fmaf(lre, xr, fmaf(-lim, xi, br[j]));
    const float ni = fmaf(lre, xi, fmaf( lim, xr, bi[j]));
    xr = nr; xi = ni;
  }

  float mre = lre, mim = lim;
#pragma unroll
  for (int s = 0; s < 4; ++s) {
    const float n2 = mre*mre - mim*mim;
    mim = 2.0f*mre*mim; mre = n2;
  }

  float Sr = xr, Si = xi;
  float pwr[6], pwi[6];
#pragma unroll
  for (int rnd = 0; rnd < 6; ++rnd) {
    pwr[rnd] = mre; pwi[rnd] = mim;
    const int off = 1 << rnd;
    const float vr = __shfl_up(Sr, off);
    const float vi = __shfl_up(Si, off);
    if (lane >= off) {
      Sr = fmaf(mre, vr, fmaf(-mim, vi, Sr));
      Si = fmaf(mre, vi, fmaf( mim, vr, Si));
    }
    const float n2 = mre*mre - mim*mim;
    mim = 2.0f*mre*mim; mre = n2;
  }

  __shared__ float Twr[4], Twi[4];
  if (lane == 63) { Twr[w] = Sr; Twi[w] = Si; }
  __syncthreads();

  float cwr = 0.0f, cwi = 0.0f;
  for (int v = 0; v < w; ++v) {
    const float nr = fmaf(mre, cwr, fmaf(-mim, cwi, Twr[v]));
    const float ni = fmaf(mre, cwi, fmaf( mim, cwr, Twi[v]));
    cwr = nr; cwi = ni;
  }

  float Er = __shfl_up(Sr, 1);
  float Ei = __shfl_up(Si, 1);
  if (lane == 0) { Er = 0.0f; Ei = 0.0f; }

  float plr = 1.0f, pli = 0.0f;
#pragma unroll
  for (int rnd = 0; rnd < 6; ++rnd) {
    if ((lane >> rnd) & 1) {
      const float nr = plr*pwr[rnd] - pli*pwi[rnd];
      const float ni = plr*pwi[rnd] + pli*pwr[rnd];
      plr = nr; pli = ni;
    }
  }

  const float cr = Er + plr*cwr - pli*cwi;
  const float ci = Ei + plr*cwi + pli*cwr;

  xr = cr; xi = ci;
  us8 o0, o1, o2, o3;
#pragma unroll
  for (int j = 0; j < 16; ++j) {
    const float nr = fmaf(lre, xr, fmaf(-lim, xi, br[j]));
    const float ni = fmaf(lre, xi, fmaf( lim, xr, bi[j]));
    xr = nr; xi = ni;
    if (j < 8) { o0[j] = f2bf(xr); o2[j] = f2bf(xi); }
    else       { o1[j-8] = f2bf(xr); o3[j-8] = f2bf(xi); }
  }
  *(us8*)&rowr[t*16]     = o0;
  *(us8*)&rowr[t*16 + 8] = o1;
  *(us8*)&rowi[t*16]     = o2;
  *(us8*)&rowi[t*16 + 8] = o3;
}

extern "C" void kernel_launch(void* const* d_in, const int* in_sizes, int n_in,
                              void* d_out, int out_size, void* d_ws, size_t ws_size,
                              hipStream_t stream) {
  (void)in_sizes; (void)n_in; (void)out_size; (void)ws_size;
  const float* in_seq = (const float*)d_in[0];
  const float* Lre    = (const float*)d_in[1];
  const float* Lim    = (const float*)d_in[2];
  const float* Bm     = (const float*)d_in[3];
  const float* Cm     = (const float*)d_in[4];
  const float* Dv     = (const float*)d_in[5];
  const float* ls     = (const float*)d_in[6];
  float* out = (float*)d_out;

  char* ws = (char*)d_ws;
  unsigned short* M1  = (unsigned short*)(ws);
  unsigned short* C2  = (unsigned short*)(ws + (512u << 10));
  float*          lam = (float*)(ws + (1u << 20));
  unsigned short* Bu  = (unsigned short*)(ws + (2u << 20));   // 32 MiB

  precompute_params<<<dim3(PP), dim3(256), 0, stream>>>(Lre, Lim, Bm, Cm, ls, M1, C2, lam);

  dim3 gg(LL/BN, HH/BM, NB);
  // G1: Bu = M1 x u   (u f32, K-strided -> fused transpose staging)
  s5_gemm_fused<true, false><<<gg, dim3(256), 0, stream>>>(M1, in_seq, Bu, nullptr, nullptr);

  s5_scan<<<dim3(PP, NB), dim3(256), 0, stream>>>(Bu, lam);

  // G2: out = gelu(C2 x xs + D*u)   (xs bf16 in Bu layout)
  s5_gemm_fused<false, true><<<gg, dim3(256), 0, stream>>>(C2, Bu, out, Dv, in_seq);
}